// Round 4
// baseline (215.590 us; speedup 1.0000x reference)
//
#include <hip/hip_runtime.h>
#include <hip/hip_bf16.h>
#include <math.h>

#define BB 4
#define TT 4096
#define DD 1024
#define HH 64
#define MTOT (BB * TT)   // 16384 rows
#define LD 72            // padded LDS row stride (shorts)
#define NCH 4            // key chunks per q row-block (1024 keys each)

typedef short short8 __attribute__((ext_vector_type(8)));
typedef float f32x4  __attribute__((ext_vector_type(4)));

__device__ inline unsigned short f2bf(float f) {
    unsigned u = __builtin_bit_cast(unsigned, f);
    unsigned r = (u + 0x7fffu + ((u >> 16) & 1u)) >> 16;
    return (unsigned short)r;
}

__device__ inline unsigned long long pack4(float a, float b, float c, float d) {
    return (unsigned long long)f2bf(a) |
           ((unsigned long long)f2bf(b) << 16) |
           ((unsigned long long)f2bf(c) << 32) |
           ((unsigned long long)f2bf(d) << 48);
}

__device__ inline short8 pack8(float4 a, float4 b) {
    short8 r;
    r[0] = (short)f2bf(a.x); r[1] = (short)f2bf(a.y);
    r[2] = (short)f2bf(a.z); r[3] = (short)f2bf(a.w);
    r[4] = (short)f2bf(b.x); r[5] = (short)f2bf(b.y);
    r[6] = (short)f2bf(b.z); r[7] = (short)f2bf(b.w);
    return r;
}

// Workspace layout (element offsets):
#define QOFF  0
#define KOFF  (MTOT * HH)
#define VOFF  (2 * MTOT * HH)
#define BF_TOTAL (3 * MTOT * HH)

// ---------------------------------------------------------------------------
// Kernel 0: transpose W (1024x64 fp32) -> Wt (64x1024 bf16), 3 matrices.
// ---------------------------------------------------------------------------
__global__ __launch_bounds__(256) void transpose_w(
    const float* __restrict__ Wq, const float* __restrict__ Wk,
    const float* __restrict__ Wv, unsigned short* __restrict__ Wt)
{
    const int w = blockIdx.y;
    const float* W = (w == 0) ? Wq : (w == 1) ? Wk : Wv;
    unsigned short* o = Wt + (size_t)w * 64 * 1024;
    const int t  = threadIdx.x;
    const int n4 = t & 15;
    const int k0 = blockIdx.x * 64 + (t >> 4) * 4;

    float v[4][4];
#pragma unroll
    for (int ii = 0; ii < 4; ++ii) {
        float4 r = *(const float4*)&W[(size_t)(k0 + ii) * HH + n4 * 4];
        v[ii][0] = r.x; v[ii][1] = r.y; v[ii][2] = r.z; v[ii][3] = r.w;
    }
#pragma unroll
    for (int cc = 0; cc < 4; ++cc) {
        unsigned long long pk = pack4(v[0][cc], v[1][cc], v[2][cc], v[3][cc]);
        *(unsigned long long*)&o[(size_t)(n4 * 4 + cc) * 1024 + k0] = pk;
    }
}

// ---------------------------------------------------------------------------
// Kernel 1: fused QKV projection, latency-pipelined.
// Grid 512 x 256 thr.  Block = 32 rows; wave kh in {0..3} owns K quarter
// (256), covers 2 row-strips (B-frag reuse), distance-1 register prefetch,
// no barriers in the k-loop.  3-round LDS tree combine across K quarters.
// ---------------------------------------------------------------------------
__global__ __launch_bounds__(256, 2) void qkv_proj(
    const float* __restrict__ x,
    const unsigned short* __restrict__ Wt,
    unsigned short* __restrict__ qkv)
{
    const int tid  = threadIdx.x;
    const int lane = tid & 63;
    const int kh   = tid >> 6;    // K quarter
    const int l15  = lane & 15;
    const int quad = lane >> 4;
    const int m0   = blockIdx.x * 32;

    __shared__ f32x4 cbuf[2][64][24];   // 48 KB combine buffers

    const float* xr = x + (size_t)(m0 + l15) * DD + kh * 256 + quad * 8;
    const unsigned short* wr = Wt + (size_t)l15 * 1024 + kh * 256 + quad * 8;

    f32x4 acc[2][12];   // [strip][w*4+nt]
#pragma unroll
    for (int st = 0; st < 2; ++st)
#pragma unroll
        for (int g = 0; g < 12; ++g) acc[st][g] = (f32x4){0.f, 0.f, 0.f, 0.f};

    float4 pa[2][2];
    short8 pb[12];
#pragma unroll
    for (int st = 0; st < 2; ++st) {
        pa[st][0] = *(const float4*)(xr + st * 16 * DD);
        pa[st][1] = *(const float4*)(xr + st * 16 * DD + 4);
    }
#pragma unroll
    for (int g = 0; g < 12; ++g)
        pb[g] = *(const short8*)(wr + (size_t)(g >> 2) * 65536 + (g & 3) * 16384);

#pragma unroll 2
    for (int step = 0; step < 8; ++step) {
        short8 af0 = pack8(pa[0][0], pa[0][1]);
        short8 af1 = pack8(pa[1][0], pa[1][1]);
        short8 cb[12];
#pragma unroll
        for (int g = 0; g < 12; ++g) cb[g] = pb[g];

        if (step < 7) {
            int ko = (step + 1) * 32;
#pragma unroll
            for (int st = 0; st < 2; ++st) {
                pa[st][0] = *(const float4*)(xr + st * 16 * DD + ko);
                pa[st][1] = *(const float4*)(xr + st * 16 * DD + ko + 4);
            }
#pragma unroll
            for (int g = 0; g < 12; ++g)
                pb[g] = *(const short8*)(wr + (size_t)(g >> 2) * 65536 + (g & 3) * 16384 + ko);
        }

#pragma unroll
        for (int g = 0; g < 12; ++g) {
            acc[0][g] = __builtin_amdgcn_mfma_f32_16x16x32_bf16(af0, cb[g], acc[0][g], 0, 0, 0);
            acc[1][g] = __builtin_amdgcn_mfma_f32_16x16x32_bf16(af1, cb[g], acc[1][g], 0, 0, 0);
        }
    }

    // tree combine: kh1->buf0, kh3->buf1; kh0+=buf0, kh2+=buf1; kh2->buf0; kh0+=buf0
    if (kh & 1) {
        int sel = kh >> 1;
#pragma unroll
        for (int st = 0; st < 2; ++st)
#pragma unroll
            for (int g = 0; g < 12; ++g) cbuf[sel][lane][st * 12 + g] = acc[st][g];
    }
    __syncthreads();
    if (!(kh & 1)) {
        int sel = kh >> 1;
#pragma unroll
        for (int st = 0; st < 2; ++st)
#pragma unroll
            for (int g = 0; g < 12; ++g) acc[st][g] += cbuf[sel][lane][st * 12 + g];
    }
    __syncthreads();
    if (kh == 2) {
#pragma unroll
        for (int st = 0; st < 2; ++st)
#pragma unroll
            for (int g = 0; g < 12; ++g) cbuf[0][lane][st * 12 + g] = acc[st][g];
    }
    __syncthreads();
    if (kh) return;
#pragma unroll
    for (int st = 0; st < 2; ++st)
#pragma unroll
        for (int g = 0; g < 12; ++g) acc[st][g] += cbuf[0][lane][st * 12 + g];

    unsigned short* q_bf  = qkv + QOFF;
    unsigned short* k_bf  = qkv + KOFF;
    unsigned short* vt_bf = qkv + VOFF;
#pragma unroll
    for (int st = 0; st < 2; ++st)
#pragma unroll
        for (int nt = 0; nt < 4; ++nt) {
            int col = nt * 16 + l15;
#pragma unroll
            for (int r = 0; r < 4; ++r) {
                int m = m0 + st * 16 + quad * 4 + r;
                q_bf[(size_t)m * HH + col] = f2bf(acc[st][nt][r]);
                k_bf[(size_t)m * HH + col] = f2bf(acc[st][4 + nt][r]);
                int b = m >> 12, t = m & 4095;
                vt_bf[(size_t)b * HH * TT + (size_t)col * TT + t] = f2bf(acc[st][8 + nt][r]);
            }
        }
}

// ---------------------------------------------------------------------------
// Kernel 2: causal flash attention, key-split, register-prefetched staging.
// Grid (qt=64, b=4, chunk=4).  exp2-domain softmax (v_exp_f32 native).
// ---------------------------------------------------------------------------
__global__ __launch_bounds__(256) void flash_attn(
    const unsigned short* __restrict__ qkv,
    float* __restrict__ Opart,
    float* __restrict__ Mpart,
    float* __restrict__ Lpart)
{
    const int qt = blockIdx.x;
    const int b  = blockIdx.y;
    const int c  = blockIdx.z;
    if (c * 16 > qt) return;
    const int j0   = c * 16;
    const int jmax = min(j0 + 16, qt + 1);

    const int tid  = threadIdx.x;
    const int lane = tid & 63;
    const int wave = tid >> 6;
    const int l15  = lane & 15;
    const int quad = lane >> 4;

    const unsigned short* q_g  = qkv + QOFF + (size_t)b * TT * HH;
    const unsigned short* k_g  = qkv + KOFF + (size_t)b * TT * HH;
    const unsigned short* vt_g = qkv + VOFF + (size_t)b * HH * TT;

    __shared__ unsigned short Ks[64 * LD];
    __shared__ unsigned short Vs[64 * LD];
    __shared__ unsigned short Ps[4 * 16 * LD];
    unsigned short* Pw = Ps + wave * 16 * LD;

    short8 qf[2];
#pragma unroll
    for (int kk = 0; kk < 2; ++kk)
        qf[kk] = *(const short8*)&q_g[(size_t)(qt * 64 + wave * 16 + l15) * HH + kk * 32 + quad * 8];

    f32x4 ov[4];
#pragma unroll
    for (int i = 0; i < 4; ++i) ov[i] = (f32x4){0.f, 0.f, 0.f, 0.f};
    float m_run = -1e30f, l_run = 0.f;

    const int srow = tid >> 3;   // 0..31
    const int seg  = tid & 7;

    // prefetch first tile into registers
    ulonglong2 kpre[2], vpre[2];
#pragma unroll
    for (int r2 = 0; r2 < 2; ++r2) {
        int row = srow + r2 * 32;
        kpre[r2] = *(const ulonglong2*)&k_g[(size_t)(j0 * 64 + row) * HH + seg * 8];
        vpre[r2] = *(const ulonglong2*)&vt_g[(size_t)row * TT + j0 * 64 + seg * 8];
    }

    const float SC = 0.125f * 1.44269504088896f;   // scale * log2(e)

    for (int j = j0; j < jmax; ++j) {
        __syncthreads();
        // commit prefetched tile to LDS
#pragma unroll
        for (int r2 = 0; r2 < 2; ++r2) {
            int row = srow + r2 * 32;
            *(ulonglong2*)&Ks[row * LD + seg * 8] = kpre[r2];
            *(ulonglong2*)&Vs[row * LD + seg * 8] = vpre[r2];
        }
        // prefetch next tile (overlaps with this tile's compute)
        if (j + 1 < jmax) {
#pragma unroll
            for (int r2 = 0; r2 < 2; ++r2) {
                int row = srow + r2 * 32;
                kpre[r2] = *(const ulonglong2*)&k_g[(size_t)((j + 1) * 64 + row) * HH + seg * 8];
                vpre[r2] = *(const ulonglong2*)&vt_g[(size_t)row * TT + (j + 1) * 64 + seg * 8];
            }
        }
        __syncthreads();

        // S^T = K · Q^T
        f32x4 st[4];
#pragma unroll
        for (int i = 0; i < 4; ++i) st[i] = (f32x4){0.f, 0.f, 0.f, 0.f};
#pragma unroll
        for (int kk = 0; kk < 2; ++kk)
#pragma unroll
            for (int mt = 0; mt < 4; ++mt) {
                short8 a = *(const short8*)&Ks[(mt * 16 + l15) * LD + kk * 32 + quad * 8];
                st[mt] = __builtin_amdgcn_mfma_f32_16x16x32_bf16(a, qf[kk], st[mt], 0, 0, 0);
            }

#pragma unroll
        for (int mt = 0; mt < 4; ++mt)
#pragma unroll
            for (int r = 0; r < 4; ++r) st[mt][r] *= SC;
        if (j == qt) {
            int qg = wave * 16 + l15;
#pragma unroll
            for (int mt = 0; mt < 4; ++mt)
#pragma unroll
                for (int r = 0; r < 4; ++r)
                    if (mt * 16 + quad * 4 + r > qg) st[mt][r] = -1e30f;
        }

        float mloc = -1e30f;
#pragma unroll
        for (int mt = 0; mt < 4; ++mt)
#pragma unroll
            for (int r = 0; r < 4; ++r) mloc = fmaxf(mloc, st[mt][r]);
        mloc = fmaxf(mloc, __shfl_xor(mloc, 16));
        mloc = fmaxf(mloc, __shfl_xor(mloc, 32));
        float m_new = fmaxf(m_run, mloc);
        float alpha = exp2f(m_run - m_new);
        m_run = m_new;

        float ssum = 0.f;
#pragma unroll
        for (int mt = 0; mt < 4; ++mt)
#pragma unroll
            for (int r = 0; r < 4; ++r) {
                float p = exp2f(st[mt][r] - m_new);
                st[mt][r] = p;
                ssum += p;
            }
        ssum += __shfl_xor(ssum, 16);
        ssum += __shfl_xor(ssum, 32);
        l_run = l_run * alpha + ssum;

#pragma unroll
        for (int mt = 0; mt < 4; ++mt)
            *(unsigned long long*)&Pw[l15 * LD + mt * 16 + quad * 4] =
                pack4(st[mt][0], st[mt][1], st[mt][2], st[mt][3]);

        float a4[4];
#pragma unroll
        for (int r = 0; r < 4; ++r) a4[r] = __shfl(alpha, quad * 4 + r);
#pragma unroll
        for (int ht = 0; ht < 4; ++ht)
#pragma unroll
            for (int r = 0; r < 4; ++r) ov[ht][r] *= a4[r];

#pragma unroll
        for (int kk = 0; kk < 2; ++kk) {
            short8 a = *(const short8*)&Pw[l15 * LD + kk * 32 + quad * 8];
#pragma unroll
            for (int ht = 0; ht < 4; ++ht) {
                short8 bf = *(const short8*)&Vs[(ht * 16 + l15) * LD + kk * 32 + quad * 8];
                ov[ht] = __builtin_amdgcn_mfma_f32_16x16x32_bf16(a, bf, ov[ht], 0, 0, 0);
            }
        }
    }

    float* Ob = Opart + ((size_t)((b * 64 + qt) * NCH + c)) * 4096;
#pragma unroll
    for (int ht = 0; ht < 4; ++ht)
#pragma unroll
        for (int r = 0; r < 4; ++r)
            Ob[(size_t)(wave * 16 + quad * 4 + r) * HH + ht * 16 + l15] = ov[ht][r];
    if (quad == 0) {
        size_t mi = (size_t)((b * 64 + qt) * NCH + c) * 64 + wave * 16 + l15;
        Mpart[mi] = m_run;
        Lpart[mi] = l_run;
    }
}

// ---------------------------------------------------------------------------
// Kernel 3: combine partials (exp2 domain), normalize, write fp32 out.
// ---------------------------------------------------------------------------
__global__ __launch_bounds__(256) void combine(
    const float* __restrict__ Opart,
    const float* __restrict__ Mpart,
    const float* __restrict__ Lpart,
    float* __restrict__ out)
{
    const int qt = blockIdx.x;
    const int b  = blockIdx.y;
    const int nc = (qt >> 4) + 1;
    const int t  = threadIdx.x;
    const int row = t >> 2;
    const int seg = t & 3;

    const size_t base = (size_t)(b * 64 + qt) * NCH;

    float m_c[NCH], M = -1e30f;
    for (int c = 0; c < nc; ++c) {
        m_c[c] = Mpart[(base + c) * 64 + row];
        M = fmaxf(M, m_c[c]);
    }
    float L = 0.f, w_c[NCH];
    for (int c = 0; c < nc; ++c) {
        w_c[c] = exp2f(m_c[c] - M);
        L += w_c[c] * Lpart[(base + c) * 64 + row];
    }
    float invL = 1.0f / L;

    f32x4 o[4];
#pragma unroll
    for (int i = 0; i < 4; ++i) o[i] = (f32x4){0.f, 0.f, 0.f, 0.f};
    for (int c = 0; c < nc; ++c) {
        const float* Ob = Opart + (base + c) * 4096 + (size_t)row * HH + seg * 16;
#pragma unroll
        for (int i = 0; i < 4; ++i) {
            f32x4 v = *(const f32x4*)(Ob + i * 4);
            o[i] += v * w_c[c];
        }
    }
    float* op = out + ((size_t)b * TT + qt * 64 + row) * HH + seg * 16;
#pragma unroll
    for (int i = 0; i < 4; ++i)
        *(f32x4*)(op + i * 4) = o[i] * invL;
}

extern "C" void kernel_launch(void* const* d_in, const int* in_sizes, int n_in,
                              void* d_out, int out_size, void* d_ws, size_t ws_size,
                              hipStream_t stream) {
    const float* x  = (const float*)d_in[0];
    const float* Wq = (const float*)d_in[1];
    const float* Wk = (const float*)d_in[2];
    const float* Wv = (const float*)d_in[3];
    float* out = (float*)d_out;

    unsigned short* qkv = (unsigned short*)d_ws;                 // 6.29 MB bf16
    float* Opart = (float*)((char*)d_ws + BF_TOTAL * 2);         // 16.78 MB
    float* Mpart = Opart + (size_t)BB * 64 * NCH * 4096;
    float* Lpart = Mpart + (size_t)BB * 64 * NCH * 64;

    unsigned short* Wt = (unsigned short*)d_out;  // pre-scratch; overwritten later

    transpose_w<<<dim3(16, 3), 256, 0, stream>>>(Wq, Wk, Wv, Wt);
    qkv_proj<<<dim3(MTOT / 32), 256, 0, stream>>>(x, Wt, qkv);
    flash_attn<<<dim3(64, BB, NCH), 256, 0, stream>>>(qkv, Opart, Mpart, Lpart);
    combine<<<dim3(64, BB), 256, 0, stream>>>(Opart, Mpart, Lpart, out);
}

// Round 6
// 214.162 us; speedup vs baseline: 1.0067x; 1.0067x over previous
//
#include <hip/hip_runtime.h>
#include <hip/hip_bf16.h>
#include <math.h>

#define BB 4
#define TT 4096
#define DD 1024
#define HH 64
#define MTOT (BB * TT)   // 16384 rows
#define LD 72            // padded LDS row stride (shorts), 144 B = 16B-aligned
#define NCH 4            // key chunks per q row-block (1024 keys each)

typedef short short8 __attribute__((ext_vector_type(8)));
typedef float f32x4  __attribute__((ext_vector_type(4)));

__device__ __forceinline__ unsigned short f2bf(float f) {
    unsigned u = __builtin_bit_cast(unsigned, f);
    unsigned r = (u + 0x7fffu + ((u >> 16) & 1u)) >> 16;
    return (unsigned short)r;
}

__device__ __forceinline__ unsigned long long pack4(float a, float b, float c, float d) {
    return (unsigned long long)f2bf(a) |
           ((unsigned long long)f2bf(b) << 16) |
           ((unsigned long long)f2bf(c) << 32) |
           ((unsigned long long)f2bf(d) << 48);
}

__device__ __forceinline__ short8 pack8(float4 a, float4 b) {
    short8 r;
    r[0] = (short)f2bf(a.x); r[1] = (short)f2bf(a.y);
    r[2] = (short)f2bf(a.z); r[3] = (short)f2bf(a.w);
    r[4] = (short)f2bf(b.x); r[5] = (short)f2bf(b.y);
    r[6] = (short)f2bf(b.z); r[7] = (short)f2bf(b.w);
    return r;
}

// Workspace layout — byte-identical to the R3/R4 passing rounds (23,593,472 B)
#define QOFF  0
#define KOFF  (MTOT * HH)
#define VOFF  (2 * MTOT * HH)
#define BF_TOTAL (3 * MTOT * HH)

// ---------------------------------------------------------------------------
// Kernel 0: transpose W (1024x64 fp32) -> Wt (64x1024 bf16), 3 matrices.
// (proven R2-R4)
// ---------------------------------------------------------------------------
__global__ __launch_bounds__(256) void transpose_w(
    const float* __restrict__ Wq, const float* __restrict__ Wk,
    const float* __restrict__ Wv, unsigned short* __restrict__ Wt)
{
    const int w = blockIdx.y;
    const float* W = (w == 0) ? Wq : (w == 1) ? Wk : Wv;
    unsigned short* o = Wt + (size_t)w * 64 * 1024;
    const int t  = threadIdx.x;
    const int n4 = t & 15;
    const int k0 = blockIdx.x * 64 + (t >> 4) * 4;

    float v[4][4];
#pragma unroll
    for (int ii = 0; ii < 4; ++ii) {
        float4 r = *(const float4*)&W[(size_t)(k0 + ii) * HH + n4 * 4];
        v[ii][0] = r.x; v[ii][1] = r.y; v[ii][2] = r.z; v[ii][3] = r.w;
    }
#pragma unroll
    for (int cc = 0; cc < 4; ++cc) {
        unsigned long long pk = pack4(v[0][cc], v[1][cc], v[2][cc], v[3][cc]);
        *(unsigned long long*)&o[(size_t)(n4 * 4 + cc) * 1024 + k0] = pk;
    }
}

// ---------------------------------------------------------------------------
// Kernel 1: fused QKV projection, N-split (race-free: no LDS, no barriers).
// Grid 1024 x 256.  Block = 16 rows of x.  Wave w owns output col-tiles
// g = 3w..3w+2 of the 12 (Q|K|V x 4 tiles of 16 cols); all waves share the
// block's 16 x-rows (L1/L2 hits).  Distance-1 prefetch on A and B.
// ---------------------------------------------------------------------------
__global__ __launch_bounds__(256) void qkv_proj(
    const float* __restrict__ x,
    const unsigned short* __restrict__ Wt,
    unsigned short* __restrict__ qkv)
{
    const int tid  = threadIdx.x;
    const int lane = tid & 63;
    const int wave = tid >> 6;
    const int l15  = lane & 15;
    const int quad = lane >> 4;
    const int m0   = blockIdx.x * 16;
    const int g0   = wave * 3;

    const float* xr = x + (size_t)(m0 + l15) * DD + quad * 8;
    const unsigned short* wp[3];
#pragma unroll
    for (int i = 0; i < 3; ++i) {
        int g = g0 + i;
        wp[i] = Wt + (size_t)(g >> 2) * 65536 + (size_t)((g & 3) * 16 + l15) * 1024 + quad * 8;
    }

    f32x4 acc[3];
#pragma unroll
    for (int i = 0; i < 3; ++i) acc[i] = (f32x4){0.f, 0.f, 0.f, 0.f};

    float4 xa0 = *(const float4*)(xr);
    float4 xa1 = *(const float4*)(xr + 4);
    short8 ba[3];
#pragma unroll
    for (int i = 0; i < 3; ++i) ba[i] = *(const short8*)(wp[i]);

#pragma unroll 4
    for (int s = 0; s < 32; ++s) {
        float4 c0 = xa0, c1 = xa1;
        short8 cb[3];
#pragma unroll
        for (int i = 0; i < 3; ++i) cb[i] = ba[i];

        if (s < 31) {
            xa0 = *(const float4*)(xr + (s + 1) * 32);
            xa1 = *(const float4*)(xr + (s + 1) * 32 + 4);
#pragma unroll
            for (int i = 0; i < 3; ++i) ba[i] = *(const short8*)(wp[i] + (s + 1) * 32);
        }

        short8 af = pack8(c0, c1);
#pragma unroll
        for (int i = 0; i < 3; ++i)
            acc[i] = __builtin_amdgcn_mfma_f32_16x16x32_bf16(af, cb[i], acc[i], 0, 0, 0);
    }

    unsigned short* q_bf  = qkv + QOFF;
    unsigned short* k_bf  = qkv + KOFF;
    unsigned short* vt_bf = qkv + VOFF;
#pragma unroll
    for (int i = 0; i < 3; ++i) {
        int g = g0 + i, w = g >> 2, col = (g & 3) * 16 + l15;
#pragma unroll
        for (int r = 0; r < 4; ++r) {
            int m = m0 + quad * 4 + r;
            unsigned short bv = f2bf(acc[i][r]);
            if (w == 0)      q_bf[(size_t)m * HH + col] = bv;
            else if (w == 1) k_bf[(size_t)m * HH + col] = bv;
            else {
                int b = m >> 12, t = m & 4095;
                vt_bf[(size_t)b * HH * TT + (size_t)col * TT + t] = bv;
            }
        }
    }
}

// ---------------------------------------------------------------------------
// Kernel 2: causal flash attention, key-split NCH=4, 2-tile staging rounds.
// Heavy-first dispatch: qt = 63 - blockIdx.x so diagonal blocks start early.
// Staging = proven R3 ds_write path, hoisted to 128 keys per barrier pair.
// ---------------------------------------------------------------------------
__global__ __launch_bounds__(256) void flash_attn(
    const unsigned short* __restrict__ qkv,
    float* __restrict__ Opart,
    float* __restrict__ Mpart,
    float* __restrict__ Lpart)
{
    const int qt = 63 - blockIdx.x;   // heavy blocks dispatch first
    const int b  = blockIdx.y;
    const int c  = blockIdx.z;
    if (c * 16 > qt) return;
    const int j0   = c * 16;
    const int jmax = min(j0 + 16, qt + 1);

    const int tid  = threadIdx.x;
    const int lane = tid & 63;
    const int wave = tid >> 6;
    const int l15  = lane & 15;
    const int quad = lane >> 4;

    const unsigned short* q_g  = qkv + QOFF + (size_t)b * TT * HH;
    const unsigned short* k_g  = qkv + KOFF + (size_t)b * TT * HH;
    const unsigned short* vt_g = qkv + VOFF + (size_t)b * HH * TT;

    __shared__ unsigned short Ks[128 * LD];     // 2 K tiles, [key][h], stride 72
    __shared__ unsigned short Vs[64 * 136];     // V^T, [h][2*64 keys], stride 136
    __shared__ unsigned short Ps[4 * 16 * LD];  // per-wave P strips
    unsigned short* Pw = Ps + wave * 16 * LD;

    short8 qf[2];
#pragma unroll
    for (int kk = 0; kk < 2; ++kk)
        qf[kk] = *(const short8*)&q_g[(size_t)(qt * 64 + wave * 16 + l15) * HH + kk * 32 + quad * 8];

    f32x4 ov[4];
#pragma unroll
    for (int i = 0; i < 4; ++i) ov[i] = (f32x4){0.f, 0.f, 0.f, 0.f};
    float m_run = -1e30f, l_run = 0.f;

    const int srow = tid >> 3;   // 0..31
    const int seg  = tid & 7;    // 16B segment

    const float SC = 0.125f * 1.44269504088896f;   // scale * log2(e)

    for (int jr = j0; jr < jmax; jr += 2) {
        const int nrow = min(jmax - jr, 2) * 64;   // 64 or 128 keys this round
        __syncthreads();   // all waves done reading previous round's Ks/Vs

        // ---- stage K rows [0, nrow): 16B per store, (row+seg)%8 bank windows
#pragma unroll
        for (int r4 = 0; r4 < 4; ++r4) {
            int row = srow + r4 * 32;
            if (row < nrow)
                *(ulonglong2*)&Ks[row * LD + seg * 8] =
                    *(const ulonglong2*)&k_g[(size_t)(jr * 64 + row) * HH + seg * 8];
        }
        // ---- stage V^T cols [0, nrow) for all 64 h rows
#pragma unroll
        for (int c2 = 0; c2 < 2; ++c2) {
            int chunk = seg + c2 * 8;            // 0..15
            if (chunk * 8 < nrow) {
#pragma unroll
                for (int r2 = 0; r2 < 2; ++r2) {
                    int h = srow + r2 * 32;
                    *(ulonglong2*)&Vs[h * 136 + chunk * 8] =
                        *(const ulonglong2*)&vt_g[(size_t)h * TT + jr * 64 + chunk * 8];
                }
            }
        }
        __syncthreads();

        const int jend = min(jr + 2, jmax);
        for (int j = jr; j < jend; ++j) {
            const int tl = (j - jr) * 64;

            // S^T = K · Q^T  (wave: 64 keys x 16 q)
            f32x4 st[4];
#pragma unroll
            for (int i = 0; i < 4; ++i) st[i] = (f32x4){0.f, 0.f, 0.f, 0.f};
#pragma unroll
            for (int kk = 0; kk < 2; ++kk)
#pragma unroll
                for (int mt = 0; mt < 4; ++mt) {
                    short8 a = *(const short8*)&Ks[(tl + mt * 16 + l15) * LD + kk * 32 + quad * 8];
                    st[mt] = __builtin_amdgcn_mfma_f32_16x16x32_bf16(a, qf[kk], st[mt], 0, 0, 0);
                }

#pragma unroll
            for (int mt = 0; mt < 4; ++mt)
#pragma unroll
                for (int r = 0; r < 4; ++r) st[mt][r] *= SC;
            if (j == qt) {
                int qg = wave * 16 + l15;
#pragma unroll
                for (int mt = 0; mt < 4; ++mt)
#pragma unroll
                    for (int r = 0; r < 4; ++r)
                        if (mt * 16 + quad * 4 + r > qg) st[mt][r] = -1e30f;
            }

            // online softmax for q = l15 (reduce across quads)
            float mloc = -1e30f;
#pragma unroll
            for (int mt = 0; mt < 4; ++mt)
#pragma unroll
                for (int r = 0; r < 4; ++r) mloc = fmaxf(mloc, st[mt][r]);
            mloc = fmaxf(mloc, __shfl_xor(mloc, 16));
            mloc = fmaxf(mloc, __shfl_xor(mloc, 32));
            float m_new = fmaxf(m_run, mloc);
            float alpha = exp2f(m_run - m_new);
            m_run = m_new;

            float ssum = 0.f;
#pragma unroll
            for (int mt = 0; mt < 4; ++mt)
#pragma unroll
                for (int r = 0; r < 4; ++r) {
                    float p = exp2f(st[mt][r] - m_new);
                    st[mt][r] = p;
                    ssum += p;
                }
            ssum += __shfl_xor(ssum, 16);
            ssum += __shfl_xor(ssum, 32);
            l_run = l_run * alpha + ssum;

            // P -> per-wave LDS strip in A-operand order (no barrier needed)
#pragma unroll
            for (int mt = 0; mt < 4; ++mt)
                *(unsigned long long*)&Pw[l15 * LD + mt * 16 + quad * 4] =
                    pack4(st[mt][0], st[mt][1], st[mt][2], st[mt][3]);

            // rescale O
            float a4[4];
#pragma unroll
            for (int r = 0; r < 4; ++r) a4[r] = __shfl(alpha, quad * 4 + r);
#pragma unroll
            for (int ht = 0; ht < 4; ++ht)
#pragma unroll
                for (int r = 0; r < 4; ++r) ov[ht][r] *= a4[r];

            // O += P · V
#pragma unroll
            for (int kk = 0; kk < 2; ++kk) {
                short8 a = *(const short8*)&Pw[l15 * LD + kk * 32 + quad * 8];
#pragma unroll
                for (int ht = 0; ht < 4; ++ht) {
                    short8 bf = *(const short8*)&Vs[(ht * 16 + l15) * 136 + tl + kk * 32 + quad * 8];
                    ov[ht] = __builtin_amdgcn_mfma_f32_16x16x32_bf16(a, bf, ov[ht], 0, 0, 0);
                }
            }
        }
    }

    // write partials (unnormalized, fp32 — proven R3/R4 path)
    float* Ob = Opart + ((size_t)((b * 64 + qt) * NCH + c)) * 4096;
#pragma unroll
    for (int ht = 0; ht < 4; ++ht)
#pragma unroll
        for (int r = 0; r < 4; ++r)
            Ob[(size_t)(wave * 16 + quad * 4 + r) * HH + ht * 16 + l15] = ov[ht][r];
    if (quad == 0) {
        size_t mi = (size_t)((b * 64 + qt) * NCH + c) * 64 + wave * 16 + l15;
        Mpart[mi] = m_run;
        Lpart[mi] = l_run;
    }
}

// ---------------------------------------------------------------------------
// Kernel 3: combine partials (exp2 domain), normalize, write fp32 out.
// (proven R4 fp32 version, verbatim)
// ---------------------------------------------------------------------------
__global__ __launch_bounds__(256) void combine(
    const float* __restrict__ Opart,
    const float* __restrict__ Mpart,
    const float* __restrict__ Lpart,
    float* __restrict__ out)
{
    const int qt = blockIdx.x;
    const int b  = blockIdx.y;
    const int nc = (qt >> 4) + 1;
    const int t  = threadIdx.x;
    const int row = t >> 2;
    const int seg = t & 3;

    const size_t base = (size_t)(b * 64 + qt) * NCH;

    float m_c[NCH], M = -1e30f;
    for (int c = 0; c < nc; ++c) {
        m_c[c] = Mpart[(base + c) * 64 + row];
        M = fmaxf(M, m_c[c]);
    }
    float L = 0.f, w_c[NCH];
    for (int c = 0; c < nc; ++c) {
        w_c[c] = exp2f(m_c[c] - M);
        L += w_c[c] * Lpart[(base + c) * 64 + row];
    }
    float invL = 1.0f / L;

    f32x4 o[4];
#pragma unroll
    for (int i = 0; i < 4; ++i) o[i] = (f32x4){0.f, 0.f, 0.f, 0.f};
    for (int c = 0; c < nc; ++c) {
        const float* Ob = Opart + (base + c) * 4096 + (size_t)row * HH + seg * 16;
#pragma unroll
        for (int i = 0; i < 4; ++i) {
            f32x4 v = *(const f32x4*)(Ob + i * 4);
            o[i] += v * w_c[c];
        }
    }
    float* op = out + ((size_t)b * TT + qt * 64 + row) * HH + seg * 16;
#pragma unroll
    for (int i = 0; i < 4; ++i)
        *(f32x4*)(op + i * 4) = o[i] * invL;
}

extern "C" void kernel_launch(void* const* d_in, const int* in_sizes, int n_in,
                              void* d_out, int out_size, void* d_ws, size_t ws_size,
                              hipStream_t stream) {
    const float* x  = (const float*)d_in[0];
    const float* Wq = (const float*)d_in[1];
    const float* Wk = (const float*)d_in[2];
    const float* Wv = (const float*)d_in[3];
    float* out = (float*)d_out;

    unsigned short* qkv = (unsigned short*)d_ws;                 // 6.29 MB bf16
    float* Opart = (float*)((char*)d_ws + BF_TOTAL * 2);         // 16.78 MB fp32
    float* Mpart = Opart + (size_t)BB * 64 * NCH * 4096;         // 0.26 MB
    float* Lpart = Mpart + (size_t)BB * 64 * NCH * 64;           // 0.26 MB

    unsigned short* Wt = (unsigned short*)d_out;  // pre-scratch; combine overwrites

    transpose_w<<<dim3(16, 3), 256, 0, stream>>>(Wq, Wk, Wv, Wt);
    qkv_proj<<<dim3(MTOT / 16), 256, 0, stream>>>(x, Wt, qkv);
    flash_attn<<<dim3(64, BB, NCH), 256, 0, stream>>>(qkv, Opart, Mpart, Lpart);
    combine<<<dim3(64, BB), 256, 0, stream>>>(Opart, Mpart, Lpart, out);
}

// Round 7
// 213.014 us; speedup vs baseline: 1.0121x; 1.0054x over previous
//
#include <hip/hip_runtime.h>
#include <hip/hip_bf16.h>
#include <math.h>

#define BB 4
#define TT 4096
#define DD 1024
#define HH 64
#define MTOT (BB * TT)   // 16384 rows
#define LD 72            // padded LDS row stride (shorts), 144 B = 16B-aligned
#define NCH 4            // key chunks per q row-block (1024 keys each)

typedef short short8 __attribute__((ext_vector_type(8)));
typedef float f32x4  __attribute__((ext_vector_type(4)));

__device__ __forceinline__ unsigned short f2bf(float f) {
    unsigned u = __builtin_bit_cast(unsigned, f);
    unsigned r = (u + 0x7fffu + ((u >> 16) & 1u)) >> 16;
    return (unsigned short)r;
}

__device__ __forceinline__ unsigned long long pack4(float a, float b, float c, float d) {
    return (unsigned long long)f2bf(a) |
           ((unsigned long long)f2bf(b) << 16) |
           ((unsigned long long)f2bf(c) << 32) |
           ((unsigned long long)f2bf(d) << 48);
}

__device__ __forceinline__ short8 pack8(float4 a, float4 b) {
    short8 r;
    r[0] = (short)f2bf(a.x); r[1] = (short)f2bf(a.y);
    r[2] = (short)f2bf(a.z); r[3] = (short)f2bf(a.w);
    r[4] = (short)f2bf(b.x); r[5] = (short)f2bf(b.y);
    r[6] = (short)f2bf(b.z); r[7] = (short)f2bf(b.w);
    return r;
}

// Workspace layout — byte-identical to R3/R4/R6 passing rounds (23,593,472 B)
#define QOFF  0
#define KOFF  (MTOT * HH)
#define VOFF  (2 * MTOT * HH)
#define BF_TOTAL (3 * MTOT * HH)

// ---------------------------------------------------------------------------
// Kernel 0: transpose W (1024x64 fp32) -> Wt (64x1024 bf16), 3 matrices.
// (proven R2-R6, verbatim)
// ---------------------------------------------------------------------------
__global__ __launch_bounds__(256) void transpose_w(
    const float* __restrict__ Wq, const float* __restrict__ Wk,
    const float* __restrict__ Wv, unsigned short* __restrict__ Wt)
{
    const int w = blockIdx.y;
    const float* W = (w == 0) ? Wq : (w == 1) ? Wk : Wv;
    unsigned short* o = Wt + (size_t)w * 64 * 1024;
    const int t  = threadIdx.x;
    const int n4 = t & 15;
    const int k0 = blockIdx.x * 64 + (t >> 4) * 4;

    float v[4][4];
#pragma unroll
    for (int ii = 0; ii < 4; ++ii) {
        float4 r = *(const float4*)&W[(size_t)(k0 + ii) * HH + n4 * 4];
        v[ii][0] = r.x; v[ii][1] = r.y; v[ii][2] = r.z; v[ii][3] = r.w;
    }
#pragma unroll
    for (int cc = 0; cc < 4; ++cc) {
        unsigned long long pk = pack4(v[0][cc], v[1][cc], v[2][cc], v[3][cc]);
        *(unsigned long long*)&o[(size_t)(n4 * 4 + cc) * 1024 + k0] = pk;
    }
}

// ---------------------------------------------------------------------------
// Kernel 1: fused QKV projection, N-split, DEEP-BATCH pipelined.
// Grid 1024 x 256.  Block = 16 rows of x; wave w owns output col-tiles
// g = 3w..3w+2 (race-free, no LDS/barriers).  k processed in chunks of 128:
// all 20 loads of chunk c+1 (8 x-float4 + 12 W-short8 = 20 KB/wave in
// flight) issue before chunk c's compute -> one vmcnt wait per chunk, not
// per 32-k step.  This is the in-flight-bytes fix for the 500 GB/s plateau.
// ---------------------------------------------------------------------------
__global__ __launch_bounds__(256) void qkv_proj(
    const float* __restrict__ x,
    const unsigned short* __restrict__ Wt,
    unsigned short* __restrict__ qkv)
{
    const int tid  = threadIdx.x;
    const int lane = tid & 63;
    const int wave = tid >> 6;
    const int l15  = lane & 15;
    const int quad = lane >> 4;
    const int m0   = blockIdx.x * 16;
    const int g0   = wave * 3;

    const float* xr = x + (size_t)(m0 + l15) * DD + quad * 8;
    const unsigned short* wp[3];
#pragma unroll
    for (int i = 0; i < 3; ++i) {
        int g = g0 + i;
        wp[i] = Wt + (size_t)(g >> 2) * 65536 + (size_t)((g & 3) * 16 + l15) * 1024 + quad * 8;
    }

    f32x4 acc[3];
#pragma unroll
    for (int i = 0; i < 3; ++i) acc[i] = (f32x4){0.f, 0.f, 0.f, 0.f};

    float4 xb[2][8];   // double-buffered x chunk: 4 steps x 2 float4
    short8 wb[2][12];  // double-buffered W chunk: 3 tiles x 4 steps

    // prologue: chunk 0 (k = 0..127)
#pragma unroll
    for (int s = 0; s < 4; ++s) {
        xb[0][2 * s]     = *(const float4*)(xr + s * 32);
        xb[0][2 * s + 1] = *(const float4*)(xr + s * 32 + 4);
    }
#pragma unroll
    for (int i = 0; i < 3; ++i)
#pragma unroll
        for (int s = 0; s < 4; ++s)
            wb[0][i * 4 + s] = *(const short8*)(wp[i] + s * 32);

#pragma unroll
    for (int c = 0; c < 8; ++c) {
        const int cur = c & 1, nxt = cur ^ 1;
        if (c < 7) {
            const int ko = (c + 1) * 128;
#pragma unroll
            for (int s = 0; s < 4; ++s) {
                xb[nxt][2 * s]     = *(const float4*)(xr + ko + s * 32);
                xb[nxt][2 * s + 1] = *(const float4*)(xr + ko + s * 32 + 4);
            }
#pragma unroll
            for (int i = 0; i < 3; ++i)
#pragma unroll
                for (int s = 0; s < 4; ++s)
                    wb[nxt][i * 4 + s] = *(const short8*)(wp[i] + ko + s * 32);
        }
#pragma unroll
        for (int s = 0; s < 4; ++s) {
            short8 af = pack8(xb[cur][2 * s], xb[cur][2 * s + 1]);
#pragma unroll
            for (int i = 0; i < 3; ++i)
                acc[i] = __builtin_amdgcn_mfma_f32_16x16x32_bf16(af, wb[cur][i * 4 + s], acc[i], 0, 0, 0);
        }
    }

    unsigned short* q_bf  = qkv + QOFF;
    unsigned short* k_bf  = qkv + KOFF;
    unsigned short* vt_bf = qkv + VOFF;
#pragma unroll
    for (int i = 0; i < 3; ++i) {
        int g = g0 + i, w = g >> 2, col = (g & 3) * 16 + l15;
#pragma unroll
        for (int r = 0; r < 4; ++r) {
            int m = m0 + quad * 4 + r;
            unsigned short bv = f2bf(acc[i][r]);
            if (w == 0)      q_bf[(size_t)m * HH + col] = bv;
            else if (w == 1) k_bf[(size_t)m * HH + col] = bv;
            else {
                int b = m >> 12, t = m & 4095;
                vt_bf[(size_t)b * HH * TT + (size_t)col * TT + t] = bv;
            }
        }
    }
}

// ---------------------------------------------------------------------------
// Kernel 2: causal flash attention, key-split NCH=4, 2-tile staging rounds.
// (byte-identical to passing R6)
// ---------------------------------------------------------------------------
__global__ __launch_bounds__(256) void flash_attn(
    const unsigned short* __restrict__ qkv,
    float* __restrict__ Opart,
    float* __restrict__ Mpart,
    float* __restrict__ Lpart)
{
    const int qt = 63 - blockIdx.x;   // heavy blocks dispatch first
    const int b  = blockIdx.y;
    const int c  = blockIdx.z;
    if (c * 16 > qt) return;
    const int j0   = c * 16;
    const int jmax = min(j0 + 16, qt + 1);

    const int tid  = threadIdx.x;
    const int lane = tid & 63;
    const int wave = tid >> 6;
    const int l15  = lane & 15;
    const int quad = lane >> 4;

    const unsigned short* q_g  = qkv + QOFF + (size_t)b * TT * HH;
    const unsigned short* k_g  = qkv + KOFF + (size_t)b * TT * HH;
    const unsigned short* vt_g = qkv + VOFF + (size_t)b * HH * TT;

    __shared__ unsigned short Ks[128 * LD];     // 2 K tiles, [key][h], stride 72
    __shared__ unsigned short Vs[64 * 136];     // V^T, [h][2*64 keys], stride 136
    __shared__ unsigned short Ps[4 * 16 * LD];  // per-wave P strips
    unsigned short* Pw = Ps + wave * 16 * LD;

    short8 qf[2];
#pragma unroll
    for (int kk = 0; kk < 2; ++kk)
        qf[kk] = *(const short8*)&q_g[(size_t)(qt * 64 + wave * 16 + l15) * HH + kk * 32 + quad * 8];

    f32x4 ov[4];
#pragma unroll
    for (int i = 0; i < 4; ++i) ov[i] = (f32x4){0.f, 0.f, 0.f, 0.f};
    float m_run = -1e30f, l_run = 0.f;

    const int srow = tid >> 3;   // 0..31
    const int seg  = tid & 7;    // 16B segment

    const float SC = 0.125f * 1.44269504088896f;   // scale * log2(e)

    for (int jr = j0; jr < jmax; jr += 2) {
        const int nrow = min(jmax - jr, 2) * 64;   // 64 or 128 keys this round
        __syncthreads();   // all waves done reading previous round's Ks/Vs

#pragma unroll
        for (int r4 = 0; r4 < 4; ++r4) {
            int row = srow + r4 * 32;
            if (row < nrow)
                *(ulonglong2*)&Ks[row * LD + seg * 8] =
                    *(const ulonglong2*)&k_g[(size_t)(jr * 64 + row) * HH + seg * 8];
        }
#pragma unroll
        for (int c2 = 0; c2 < 2; ++c2) {
            int chunk = seg + c2 * 8;            // 0..15
            if (chunk * 8 < nrow) {
#pragma unroll
                for (int r2 = 0; r2 < 2; ++r2) {
                    int h = srow + r2 * 32;
                    *(ulonglong2*)&Vs[h * 136 + chunk * 8] =
                        *(const ulonglong2*)&vt_g[(size_t)h * TT + jr * 64 + chunk * 8];
                }
            }
        }
        __syncthreads();

        const int jend = min(jr + 2, jmax);
        for (int j = jr; j < jend; ++j) {
            const int tl = (j - jr) * 64;

            f32x4 st[4];
#pragma unroll
            for (int i = 0; i < 4; ++i) st[i] = (f32x4){0.f, 0.f, 0.f, 0.f};
#pragma unroll
            for (int kk = 0; kk < 2; ++kk)
#pragma unroll
                for (int mt = 0; mt < 4; ++mt) {
                    short8 a = *(const short8*)&Ks[(tl + mt * 16 + l15) * LD + kk * 32 + quad * 8];
                    st[mt] = __builtin_amdgcn_mfma_f32_16x16x32_bf16(a, qf[kk], st[mt], 0, 0, 0);
                }

#pragma unroll
            for (int mt = 0; mt < 4; ++mt)
#pragma unroll
                for (int r = 0; r < 4; ++r) st[mt][r] *= SC;
            if (j == qt) {
                int qg = wave * 16 + l15;
#pragma unroll
                for (int mt = 0; mt < 4; ++mt)
#pragma unroll
                    for (int r = 0; r < 4; ++r)
                        if (mt * 16 + quad * 4 + r > qg) st[mt][r] = -1e30f;
            }

            float mloc = -1e30f;
#pragma unroll
            for (int mt = 0; mt < 4; ++mt)
#pragma unroll
                for (int r = 0; r < 4; ++r) mloc = fmaxf(mloc, st[mt][r]);
            mloc = fmaxf(mloc, __shfl_xor(mloc, 16));
            mloc = fmaxf(mloc, __shfl_xor(mloc, 32));
            float m_new = fmaxf(m_run, mloc);
            float alpha = exp2f(m_run - m_new);
            m_run = m_new;

            float ssum = 0.f;
#pragma unroll
            for (int mt = 0; mt < 4; ++mt)
#pragma unroll
                for (int r = 0; r < 4; ++r) {
                    float p = exp2f(st[mt][r] - m_new);
                    st[mt][r] = p;
                    ssum += p;
                }
            ssum += __shfl_xor(ssum, 16);
            ssum += __shfl_xor(ssum, 32);
            l_run = l_run * alpha + ssum;

#pragma unroll
            for (int mt = 0; mt < 4; ++mt)
                *(unsigned long long*)&Pw[l15 * LD + mt * 16 + quad * 4] =
                    pack4(st[mt][0], st[mt][1], st[mt][2], st[mt][3]);

            float a4[4];
#pragma unroll
            for (int r = 0; r < 4; ++r) a4[r] = __shfl(alpha, quad * 4 + r);
#pragma unroll
            for (int ht = 0; ht < 4; ++ht)
#pragma unroll
                for (int r = 0; r < 4; ++r) ov[ht][r] *= a4[r];

#pragma unroll
            for (int kk = 0; kk < 2; ++kk) {
                short8 a = *(const short8*)&Pw[l15 * LD + kk * 32 + quad * 8];
#pragma unroll
                for (int ht = 0; ht < 4; ++ht) {
                    short8 bf = *(const short8*)&Vs[(ht * 16 + l15) * 136 + tl + kk * 32 + quad * 8];
                    ov[ht] = __builtin_amdgcn_mfma_f32_16x16x32_bf16(a, bf, ov[ht], 0, 0, 0);
                }
            }
        }
    }

    float* Ob = Opart + ((size_t)((b * 64 + qt) * NCH + c)) * 4096;
#pragma unroll
    for (int ht = 0; ht < 4; ++ht)
#pragma unroll
        for (int r = 0; r < 4; ++r)
            Ob[(size_t)(wave * 16 + quad * 4 + r) * HH + ht * 16 + l15] = ov[ht][r];
    if (quad == 0) {
        size_t mi = (size_t)((b * 64 + qt) * NCH + c) * 64 + wave * 16 + l15;
        Mpart[mi] = m_run;
        Lpart[mi] = l_run;
    }
}

// ---------------------------------------------------------------------------
// Kernel 3: combine partials (exp2 domain), normalize, write fp32 out.
// (proven R4/R6, verbatim)
// ---------------------------------------------------------------------------
__global__ __launch_bounds__(256) void combine(
    const float* __restrict__ Opart,
    const float* __restrict__ Mpart,
    const float* __restrict__ Lpart,
    float* __restrict__ out)
{
    const int qt = blockIdx.x;
    const int b  = blockIdx.y;
    const int nc = (qt >> 4) + 1;
    const int t  = threadIdx.x;
    const int row = t >> 2;
    const int seg = t & 3;

    const size_t base = (size_t)(b * 64 + qt) * NCH;

    float m_c[NCH], M = -1e30f;
    for (int c = 0; c < nc; ++c) {
        m_c[c] = Mpart[(base + c) * 64 + row];
        M = fmaxf(M, m_c[c]);
    }
    float L = 0.f, w_c[NCH];
    for (int c = 0; c < nc; ++c) {
        w_c[c] = exp2f(m_c[c] - M);
        L += w_c[c] * Lpart[(base + c) * 64 + row];
    }
    float invL = 1.0f / L;

    f32x4 o[4];
#pragma unroll
    for (int i = 0; i < 4; ++i) o[i] = (f32x4){0.f, 0.f, 0.f, 0.f};
    for (int c = 0; c < nc; ++c) {
        const float* Ob = Opart + (base + c) * 4096 + (size_t)row * HH + seg * 16;
#pragma unroll
        for (int i = 0; i < 4; ++i) {
            f32x4 v = *(const f32x4*)(Ob + i * 4);
            o[i] += v * w_c[c];
        }
    }
    float* op = out + ((size_t)b * TT + qt * 64 + row) * HH + seg * 16;
#pragma unroll
    for (int i = 0; i < 4; ++i)
        *(f32x4*)(op + i * 4) = o[i] * invL;
}

extern "C" void kernel_launch(void* const* d_in, const int* in_sizes, int n_in,
                              void* d_out, int out_size, void* d_ws, size_t ws_size,
                              hipStream_t stream) {
    const float* x  = (const float*)d_in[0];
    const float* Wq = (const float*)d_in[1];
    const float* Wk = (const float*)d_in[2];
    const float* Wv = (const float*)d_in[3];
    float* out = (float*)d_out;

    unsigned short* qkv = (unsigned short*)d_ws;                 // 6.29 MB bf16
    float* Opart = (float*)((char*)d_ws + BF_TOTAL * 2);         // 16.78 MB fp32
    float* Mpart = Opart + (size_t)BB * 64 * NCH * 4096;         // 0.26 MB
    float* Lpart = Mpart + (size_t)BB * 64 * NCH * 64;           // 0.26 MB

    unsigned short* Wt = (unsigned short*)d_out;  // pre-scratch; combine overwrites

    transpose_w<<<dim3(16, 3), 256, 0, stream>>>(Wq, Wk, Wv, Wt);
    qkv_proj<<<dim3(MTOT / 16), 256, 0, stream>>>(x, Wt, qkv);
    flash_attn<<<dim3(64, BB, NCH), 256, 0, stream>>>(qkv, Opart, Mpart, Lpart);
    combine<<<dim3(64, BB), 256, 0, stream>>>(Opart, Mpart, Lpart, out);
}

// Round 8
// 189.532 us; speedup vs baseline: 1.1375x; 1.1239x over previous
//
#include <hip/hip_runtime.h>
#include <hip/hip_bf16.h>
#include <math.h>

#define BB 4
#define TT 4096
#define DD 1024
#define HH 64
#define MTOT (BB * TT)   // 16384 rows
#define LD 72            // padded LDS row stride (shorts), 144 B = 16B-aligned
#define NCH 4            // key chunks per q row-block (1024 keys each)

typedef short short8 __attribute__((ext_vector_type(8)));
typedef float f32x4  __attribute__((ext_vector_type(4)));

__device__ __forceinline__ unsigned short f2bf(float f) {
    unsigned u = __builtin_bit_cast(unsigned, f);
    unsigned r = (u + 0x7fffu + ((u >> 16) & 1u)) >> 16;
    return (unsigned short)r;
}

__device__ __forceinline__ unsigned long long pack4(float a, float b, float c, float d) {
    return (unsigned long long)f2bf(a) |
           ((unsigned long long)f2bf(b) << 16) |
           ((unsigned long long)f2bf(c) << 32) |
           ((unsigned long long)f2bf(d) << 48);
}

__device__ __forceinline__ short8 pack8(float4 a, float4 b) {
    short8 r;
    r[0] = (short)f2bf(a.x); r[1] = (short)f2bf(a.y);
    r[2] = (short)f2bf(a.z); r[3] = (short)f2bf(a.w);
    r[4] = (short)f2bf(b.x); r[5] = (short)f2bf(b.y);
    r[6] = (short)f2bf(b.z); r[7] = (short)f2bf(b.w);
    return r;
}

// Workspace layout — byte-identical to R3/R4/R6/R7 passing rounds
#define QOFF  0
#define KOFF  (MTOT * HH)
#define VOFF  (2 * MTOT * HH)
#define BF_TOTAL (3 * MTOT * HH)

// ---------------------------------------------------------------------------
// Kernel 0: transpose W (1024x64 fp32) -> Wt (64x1024 bf16), 3 matrices.
// (proven R2-R7, verbatim)
// ---------------------------------------------------------------------------
__global__ __launch_bounds__(256) void transpose_w(
    const float* __restrict__ Wq, const float* __restrict__ Wk,
    const float* __restrict__ Wv, unsigned short* __restrict__ Wt)
{
    const int w = blockIdx.y;
    const float* W = (w == 0) ? Wq : (w == 1) ? Wk : Wv;
    unsigned short* o = Wt + (size_t)w * 64 * 1024;
    const int t  = threadIdx.x;
    const int n4 = t & 15;
    const int k0 = blockIdx.x * 64 + (t >> 4) * 4;

    float v[4][4];
#pragma unroll
    for (int ii = 0; ii < 4; ++ii) {
        float4 r = *(const float4*)&W[(size_t)(k0 + ii) * HH + n4 * 4];
        v[ii][0] = r.x; v[ii][1] = r.y; v[ii][2] = r.z; v[ii][3] = r.w;
    }
#pragma unroll
    for (int cc = 0; cc < 4; ++cc) {
        unsigned long long pk = pack4(v[0][cc], v[1][cc], v[2][cc], v[3][cc]);
        *(unsigned long long*)&o[(size_t)(n4 * 4 + cc) * 1024 + k0] = pk;
    }
}

// ---------------------------------------------------------------------------
// Kernel 1: fused QKV projection as LDS-tiled GEMM (m90-style 2-barrier loop).
// C[16384,192] = x[16384,1024] @ [Wq|Wk|Wv].  Grid 512 x 256; block = 32 rows
// x 192 cols, BK=64, single-buffered LDS (A fp32 [m][k] pad+4, B bf16 [col][k]
// pad+8).  Global loads feed ds_writes (copy pattern -> compiler keeps them
// in flight); MFMA reads from LDS (fine-grained lgkmcnt).  Wave = 16-row
// strip x 6 col-tiles.  2 blocks/CU for barrier-stall overlap.
// ---------------------------------------------------------------------------
__global__ __launch_bounds__(256) void qkv_proj(
    const float* __restrict__ x,
    const unsigned short* __restrict__ Wt,
    unsigned short* __restrict__ qkv)
{
    const int tid   = threadIdx.x;
    const int lane  = tid & 63;
    const int wave  = tid >> 6;
    const int l15   = lane & 15;
    const int quad  = lane >> 4;
    const int m0    = blockIdx.x * 32;
    const int strip = wave >> 1;   // 0..1: 16-row strip
    const int gh    = wave & 1;    // 0..1: col-tile half (6 g each)

    __shared__ float          Af[32 * 68];    // [m][k] fp32, row stride 68
    __shared__ unsigned short Bs[192 * 72];   // [col][k] bf16, row stride 72

    f32x4 acc[6];
#pragma unroll
    for (int j = 0; j < 6; ++j) acc[j] = (f32x4){0.f, 0.f, 0.f, 0.f};

    const int arow0 = tid >> 4;   // A staging: row (+16 per i), seg = tid&15
    const int aseg  = tid & 15;
    const int bseg  = tid & 7;    // B staging: 16B seg within a col's 128B

    for (int c = 0; c < 16; ++c) {
        const int kc = c * 64;

        // ---- stage A tile: 32 rows x 64 k fp32 (16 KB), 2 float4/thread
#pragma unroll
        for (int i = 0; i < 2; ++i) {
            int row = arow0 + i * 16;
            float4 v = *(const float4*)&x[(size_t)(m0 + row) * DD + kc + aseg * 4];
            *(float4*)&Af[row * 68 + aseg * 4] = v;
        }
        // ---- stage B tile: 192 cols x 64 k bf16 (24 KB), 6 short8/thread
#pragma unroll
        for (int i = 0; i < 6; ++i) {
            int tau  = tid + i * 256;
            int gcol = tau >> 3;
            short8 v = *(const short8*)&Wt[(size_t)(gcol >> 6) * 65536 +
                                           (size_t)(gcol & 63) * 1024 + kc + bseg * 8];
            *(short8*)&Bs[gcol * 72 + bseg * 8] = v;
        }
        __syncthreads();

        // ---- compute: 2 k-steps x 6 col-tiles
#pragma unroll
        for (int ks = 0; ks < 2; ++ks) {
            const float* ap = &Af[(strip * 16 + l15) * 68 + ks * 32 + quad * 8];
            float4 a0 = *(const float4*)ap;
            float4 a1 = *(const float4*)(ap + 4);
            short8 af = pack8(a0, a1);
#pragma unroll
            for (int j = 0; j < 6; ++j) {
                int g = gh * 6 + j;
                short8 bf = *(const short8*)&Bs[(g * 16 + l15) * 72 + ks * 32 + quad * 8];
                acc[j] = __builtin_amdgcn_mfma_f32_16x16x32_bf16(af, bf, acc[j], 0, 0, 0);
            }
        }
        __syncthreads();
    }

    // ---- epilogue: q/k as [b t h] bf16, v transposed [b h t] bf16
    unsigned short* q_bf  = qkv + QOFF;
    unsigned short* k_bf  = qkv + KOFF;
    unsigned short* vt_bf = qkv + VOFF;
#pragma unroll
    for (int j = 0; j < 6; ++j) {
        int g = gh * 6 + j, w = g >> 2, col = (g & 3) * 16 + l15;
#pragma unroll
        for (int r = 0; r < 4; ++r) {
            int m = m0 + strip * 16 + quad * 4 + r;
            unsigned short bv = f2bf(acc[j][r]);
            if (w == 0)      q_bf[(size_t)m * HH + col] = bv;
            else if (w == 1) k_bf[(size_t)m * HH + col] = bv;
            else {
                int b = m >> 12, t = m & 4095;
                vt_bf[(size_t)b * HH * TT + (size_t)col * TT + t] = bv;
            }
        }
    }
}

// ---------------------------------------------------------------------------
// Kernel 2: causal flash attention, key-split NCH=4, 2-tile staging rounds.
// (byte-identical to passing R6/R7)
// ---------------------------------------------------------------------------
__global__ __launch_bounds__(256) void flash_attn(
    const unsigned short* __restrict__ qkv,
    float* __restrict__ Opart,
    float* __restrict__ Mpart,
    float* __restrict__ Lpart)
{
    const int qt = 63 - blockIdx.x;   // heavy blocks dispatch first
    const int b  = blockIdx.y;
    const int c  = blockIdx.z;
    if (c * 16 > qt) return;
    const int j0   = c * 16;
    const int jmax = min(j0 + 16, qt + 1);

    const int tid  = threadIdx.x;
    const int lane = tid & 63;
    const int wave = tid >> 6;
    const int l15  = lane & 15;
    const int quad = lane >> 4;

    const unsigned short* q_g  = qkv + QOFF + (size_t)b * TT * HH;
    const unsigned short* k_g  = qkv + KOFF + (size_t)b * TT * HH;
    const unsigned short* vt_g = qkv + VOFF + (size_t)b * HH * TT;

    __shared__ unsigned short Ks[128 * LD];     // 2 K tiles, [key][h], stride 72
    __shared__ unsigned short Vs[64 * 136];     // V^T, [h][2*64 keys], stride 136
    __shared__ unsigned short Ps[4 * 16 * LD];  // per-wave P strips
    unsigned short* Pw = Ps + wave * 16 * LD;

    short8 qf[2];
#pragma unroll
    for (int kk = 0; kk < 2; ++kk)
        qf[kk] = *(const short8*)&q_g[(size_t)(qt * 64 + wave * 16 + l15) * HH + kk * 32 + quad * 8];

    f32x4 ov[4];
#pragma unroll
    for (int i = 0; i < 4; ++i) ov[i] = (f32x4){0.f, 0.f, 0.f, 0.f};
    float m_run = -1e30f, l_run = 0.f;

    const int srow = tid >> 3;   // 0..31
    const int seg  = tid & 7;    // 16B segment

    const float SC = 0.125f * 1.44269504088896f;   // scale * log2(e)

    for (int jr = j0; jr < jmax; jr += 2) {
        const int nrow = min(jmax - jr, 2) * 64;   // 64 or 128 keys this round
        __syncthreads();   // all waves done reading previous round's Ks/Vs

#pragma unroll
        for (int r4 = 0; r4 < 4; ++r4) {
            int row = srow + r4 * 32;
            if (row < nrow)
                *(ulonglong2*)&Ks[row * LD + seg * 8] =
                    *(const ulonglong2*)&k_g[(size_t)(jr * 64 + row) * HH + seg * 8];
        }
#pragma unroll
        for (int c2 = 0; c2 < 2; ++c2) {
            int chunk = seg + c2 * 8;            // 0..15
            if (chunk * 8 < nrow) {
#pragma unroll
                for (int r2 = 0; r2 < 2; ++r2) {
                    int h = srow + r2 * 32;
                    *(ulonglong2*)&Vs[h * 136 + chunk * 8] =
                        *(const ulonglong2*)&vt_g[(size_t)h * TT + jr * 64 + chunk * 8];
                }
            }
        }
        __syncthreads();

        const int jend = min(jr + 2, jmax);
        for (int j = jr; j < jend; ++j) {
            const int tl = (j - jr) * 64;

            f32x4 st[4];
#pragma unroll
            for (int i = 0; i < 4; ++i) st[i] = (f32x4){0.f, 0.f, 0.f, 0.f};
#pragma unroll
            for (int kk = 0; kk < 2; ++kk)
#pragma unroll
                for (int mt = 0; mt < 4; ++mt) {
                    short8 a = *(const short8*)&Ks[(tl + mt * 16 + l15) * LD + kk * 32 + quad * 8];
                    st[mt] = __builtin_amdgcn_mfma_f32_16x16x32_bf16(a, qf[kk], st[mt], 0, 0, 0);
                }

#pragma unroll
            for (int mt = 0; mt < 4; ++mt)
#pragma unroll
                for (int r = 0; r < 4; ++r) st[mt][r] *= SC;
            if (j == qt) {
                int qg = wave * 16 + l15;
#pragma unroll
                for (int mt = 0; mt < 4; ++mt)
#pragma unroll
                    for (int r = 0; r < 4; ++r)
                        if (mt * 16 + quad * 4 + r > qg) st[mt][r] = -1e30f;
            }

            float mloc = -1e30f;
#pragma unroll
            for (int mt = 0; mt < 4; ++mt)
#pragma unroll
                for (int r = 0; r < 4; ++r) mloc = fmaxf(mloc, st[mt][r]);
            mloc = fmaxf(mloc, __shfl_xor(mloc, 16));
            mloc = fmaxf(mloc, __shfl_xor(mloc, 32));
            float m_new = fmaxf(m_run, mloc);
            float alpha = exp2f(m_run - m_new);
            m_run = m_new;

            float ssum = 0.f;
#pragma unroll
            for (int mt = 0; mt < 4; ++mt)
#pragma unroll
                for (int r = 0; r < 4; ++r) {
                    float p = exp2f(st[mt][r] - m_new);
                    st[mt][r] = p;
                    ssum += p;
                }
            ssum += __shfl_xor(ssum, 16);
            ssum += __shfl_xor(ssum, 32);
            l_run = l_run * alpha + ssum;

#pragma unroll
            for (int mt = 0; mt < 4; ++mt)
                *(unsigned long long*)&Pw[l15 * LD + mt * 16 + quad * 4] =
                    pack4(st[mt][0], st[mt][1], st[mt][2], st[mt][3]);

            float a4[4];
#pragma unroll
            for (int r = 0; r < 4; ++r) a4[r] = __shfl(alpha, quad * 4 + r);
#pragma unroll
            for (int ht = 0; ht < 4; ++ht)
#pragma unroll
                for (int r = 0; r < 4; ++r) ov[ht][r] *= a4[r];

#pragma unroll
            for (int kk = 0; kk < 2; ++kk) {
                short8 a = *(const short8*)&Pw[l15 * LD + kk * 32 + quad * 8];
#pragma unroll
                for (int ht = 0; ht < 4; ++ht) {
                    short8 bf = *(const short8*)&Vs[(ht * 16 + l15) * 136 + tl + kk * 32 + quad * 8];
                    ov[ht] = __builtin_amdgcn_mfma_f32_16x16x32_bf16(a, bf, ov[ht], 0, 0, 0);
                }
            }
        }
    }

    float* Ob = Opart + ((size_t)((b * 64 + qt) * NCH + c)) * 4096;
#pragma unroll
    for (int ht = 0; ht < 4; ++ht)
#pragma unroll
        for (int r = 0; r < 4; ++r)
            Ob[(size_t)(wave * 16 + quad * 4 + r) * HH + ht * 16 + l15] = ov[ht][r];
    if (quad == 0) {
        size_t mi = (size_t)((b * 64 + qt) * NCH + c) * 64 + wave * 16 + l15;
        Mpart[mi] = m_run;
        Lpart[mi] = l_run;
    }
}

// ---------------------------------------------------------------------------
// Kernel 3: combine partials (exp2 domain), normalize, write fp32 out.
// (proven R4/R6/R7, verbatim)
// ---------------------------------------------------------------------------
__global__ __launch_bounds__(256) void combine(
    const float* __restrict__ Opart,
    const float* __restrict__ Mpart,
    const float* __restrict__ Lpart,
    float* __restrict__ out)
{
    const int qt = blockIdx.x;
    const int b  = blockIdx.y;
    const int nc = (qt >> 4) + 1;
    const int t  = threadIdx.x;
    const int row = t >> 2;
    const int seg = t & 3;

    const size_t base = (size_t)(b * 64 + qt) * NCH;

    float m_c[NCH], M = -1e30f;
    for (int c = 0; c < nc; ++c) {
        m_c[c] = Mpart[(base + c) * 64 + row];
        M = fmaxf(M, m_c[c]);
    }
    float L = 0.f, w_c[NCH];
    for (int c = 0; c < nc; ++c) {
        w_c[c] = exp2f(m_c[c] - M);
        L += w_c[c] * Lpart[(base + c) * 64 + row];
    }
    float invL = 1.0f / L;

    f32x4 o[4];
#pragma unroll
    for (int i = 0; i < 4; ++i) o[i] = (f32x4){0.f, 0.f, 0.f, 0.f};
    for (int c = 0; c < nc; ++c) {
        const float* Ob = Opart + (base + c) * 4096 + (size_t)row * HH + seg * 16;
#pragma unroll
        for (int i = 0; i < 4; ++i) {
            f32x4 v = *(const f32x4*)(Ob + i * 4);
            o[i] += v * w_c[c];
        }
    }
    float* op = out + ((size_t)b * TT + qt * 64 + row) * HH + seg * 16;
#pragma unroll
    for (int i = 0; i < 4; ++i)
        *(f32x4*)(op + i * 4) = o[i] * invL;
}

extern "C" void kernel_launch(void* const* d_in, const int* in_sizes, int n_in,
                              void* d_out, int out_size, void* d_ws, size_t ws_size,
                              hipStream_t stream) {
    const float* x  = (const float*)d_in[0];
    const float* Wq = (const float*)d_in[1];
    const float* Wk = (const float*)d_in[2];
    const float* Wv = (const float*)d_in[3];
    float* out = (float*)d_out;

    unsigned short* qkv = (unsigned short*)d_ws;                 // 6.29 MB bf16
    float* Opart = (float*)((char*)d_ws + BF_TOTAL * 2);         // 16.78 MB fp32
    float* Mpart = Opart + (size_t)BB * 64 * NCH * 4096;         // 0.26 MB
    float* Lpart = Mpart + (size_t)BB * 64 * NCH * 64;           // 0.26 MB

    unsigned short* Wt = (unsigned short*)d_out;  // pre-scratch; combine overwrites

    transpose_w<<<dim3(16, 3), 256, 0, stream>>>(Wq, Wk, Wv, Wt);
    qkv_proj<<<dim3(MTOT / 32), 256, 0, stream>>>(x, Wt, qkv);
    flash_attn<<<dim3(64, BB, NCH), 256, 0, stream>>>(qkv, Opart, Mpart, Lpart);
    combine<<<dim3(64, BB), 256, 0, stream>>>(Opart, Mpart, Lpart, out);
}